// Round 13
// baseline (195.734 us; speedup 1.0000x reference)
//
#include <hip/hip_runtime.h>
#include <hip/hip_bf16.h>
#include <hip/hip_fp16.h>

#define SEQ_T 100
#define HID 20
#define EMB_D 50
#define VOCAB_N 50000
#define TABW 60          // tab row stride = 60 gate cols [z20|r20|h20]
#define NTILE 3125       // VOCAB_N/16
#define BBLK 782         // build_table blocks (x4 waves, 1 tile/wave)

typedef short sh8 __attribute__((ext_vector_type(8)));   // 8 bf16 bit patterns
typedef float f4  __attribute__((ext_vector_type(4)));

// ws layout (float/dword offsets). tab f16: 50000*60*2B = 6 MB.
#define OFF_U1P 0        // 600 dwords (60 cols x 10 packed f16 k-pairs, PRESCALED)
#define OFF_W2P 600
#define OFF_U2P 1200
#define OFF_B1  3600     // 120 fp32 (first 60 raw bi1 for build MFMA; last 60 br1 prescaled)
#define OFF_B2  3720     // 120 fp32 (all prescaled)
#define OFF_WD  3840     // 300 fp32
#define OFF_BD  4140     // 15 fp32
#define OFF_TAB 4160     // 50000 x 60 f16 (PRESCALED: zr cols x -log2e, h cols x 2log2e)

__device__ __forceinline__ float ldf(const void* p, int i, int isf) {
  return isf ? ((const float*)p)[i]
             : __bfloat162float(((const __hip_bfloat16*)p)[i]);
}
__device__ __forceinline__ short f2bf(float f) {   // RNE fp32->bf16 bits
  unsigned u = __float_as_uint(f);
  u += 0x7fffu + ((u >> 16) & 1u);
  return (short)(u >> 16);
}
__device__ __forceinline__ float rdl(float v, int l) {
  return __uint_as_float(__builtin_amdgcn_readlane(__float_as_uint(v), l));
}
__device__ __forceinline__ int detect_isf(const void* emb) {
  uint4 dv = ((const uint4*)emb)[threadIdx.x & 63];
  int big = 0;
#pragma unroll
  for (int i = 0; i < 4; ++i) {
    unsigned w = ((const unsigned*)&dv)[i];
    big |= (((w >> 7) & 0xFF) >= 140) | (((w >> 23) & 0xFF) >= 140);
  }
  return (__ballot(big) != 0ull) ? 1 : 0;
}
// gate scale: zr cols (0-39) -log2e, h cols (40-59) +2log2e (folded; see r24).
__device__ __forceinline__ float gsc(int col) {
  return (col < 40) ? -1.44269504f : 2.88539008f;
}

// tab = (emb @ W1 + bi1) * gsc, stored f16.
// ROUND-27: COALESCED tab stores. Old path: each lane stored 16 scalar 2B
// values at stride 120B -> ~3M scattered store transactions chip-wide; the
// BBLK 200->782 null (gap unmoved) fits a store-THROUGHPUT bound, which
// more waves can't fix. A tile is 16 consecutive vocab rows = contiguous
// 1920B of tab. New path: stage f16 results in a per-wave LDS tile (row
// stride 136B -> write banks fully spread: bank=(q*8+r*2+nt*8+c/2)%32 hits
// all 32; dword-aligned reads), then store 480 coalesced dwords (<=8/lane).
// Same f16 values -> absmax unchanged. gru_main untouched (r26, 118.5us).
__global__ __launch_bounds__(256) void build_table(
    const void* __restrict__ emb, const void* __restrict__ W1,
    const void* __restrict__ b1,
    const void* __restrict__ U1, const void* __restrict__ W2,
    const void* __restrict__ U2, const void* __restrict__ b2,
    const void* __restrict__ Wd, const void* __restrict__ bd,
    float* __restrict__ ws)
{
  const int isf = detect_isf(emb);
  if (blockIdx.x == 0) {                     // fold: weight prep
    const int t = threadIdx.x;
    unsigned* wsu = (unsigned*)ws;
    for (int i = t; i < 600; i += 256) {
      const int j = i / 10, p = i % 10;
      const int k0 = 2 * p, k1 = 2 * p + 1;
      const float s = gsc(j);
#define PK(M) ((unsigned)__half_as_ushort(__float2half_rn(ldf(M, k0 * 60 + j, isf) * s)) | \
               ((unsigned)__half_as_ushort(__float2half_rn(ldf(M, k1 * 60 + j, isf) * s)) << 16))
      wsu[OFF_U1P + i] = PK(U1);
      wsu[OFF_W2P + i] = PK(W2);
      wsu[OFF_U2P + i] = PK(U2);
#undef PK
    }
    for (int i = t; i < 120; i += 256) {
      ws[OFF_B1 + i] = ldf(b1, i, isf) * (i >= 60 ? gsc(i - 60) : 1.f);
      ws[OFF_B2 + i] = ldf(b2, i, isf) * gsc(i % 60);
    }
    for (int i = t; i < 300; i += 256) ws[OFF_WD + i] = ldf(Wd, i, isf);
    for (int i = t; i < 15;  i += 256) ws[OFF_BD + i] = ldf(bd, i, isf);
  }

  const int L = threadIdx.x & 63, q = L >> 4, c = L & 15;
  const int w = threadIdx.x >> 6;
  const int wid = blockIdx.x * 4 + w;
  unsigned short* __restrict__ tab16 = (unsigned short*)(ws + OFF_TAB);

  __shared__ int4 sB[64][8];
  __shared__ _Float16 st[4][16][68];         // row stride 136 B (see header)
  if (threadIdx.x < 64) {
#pragma unroll
    for (int nt = 0; nt < 4; ++nt) {
      const int col = nt * 16 + c;
      sh8 B0, B1;
#pragma unroll
      for (int jj = 0; jj < 8; ++jj) {
        const int k0 = q * 8 + jj, k1 = 32 + q * 8 + jj;
        B0[jj] = (col < TABW) ? f2bf(ldf(W1, k0 * TABW + col, isf)) : (short)0;
        B1[jj] = (col < TABW && k1 < EMB_D)
                     ? f2bf(ldf(W1, k1 * TABW + col, isf)) : (short)0;
      }
      sB[L][nt * 2]     = *(const int4*)&B0;
      sB[L][nt * 2 + 1] = *(const int4*)&B1;
    }
  }
  float bi[4];
#pragma unroll
  for (int nt = 0; nt < 4; ++nt) {
    const int col = nt * 16 + c;
    bi[nt] = (col < TABW) ? ldf(b1, col, isf) : 0.f;
  }
  __syncthreads();

  for (int tile = wid; tile < NTILE; tile += BBLK * 4) {
    const int v0 = tile * 16;
    sh8 A0, A1;
#pragma unroll
    for (int jj = 0; jj < 8; ++jj) { A0[jj] = 0; A1[jj] = 0; }
    if (!isf) {
      const unsigned short* eb = (const unsigned short*)emb;
      const size_t rb = (size_t)(v0 + c) * EMB_D;
#pragma unroll
      for (int i = 0; i < 4; ++i) {
        unsigned d = *(const unsigned*)(eb + rb + q * 8 + 2 * i);
        A0[2 * i] = (short)(d & 0xffff); A0[2 * i + 1] = (short)(d >> 16);
      }
      const int k1b = 32 + q * 8;
#pragma unroll
      for (int i = 0; i < 4; ++i) {
        const int k = k1b + 2 * i;
        if (k + 1 < EMB_D) {
          unsigned d = *(const unsigned*)(eb + rb + k);
          A1[2 * i] = (short)(d & 0xffff); A1[2 * i + 1] = (short)(d >> 16);
        }
      }
    } else {
      const float* ef = (const float*)emb;
      const size_t rb = (size_t)(v0 + c) * EMB_D;
#pragma unroll
      for (int jj = 0; jj < 8; ++jj) {
        const int k0 = q * 8 + jj, k1 = 32 + q * 8 + jj;
        A0[jj] = f2bf(ef[rb + k0]);
        A1[jj] = (k1 < EMB_D) ? f2bf(ef[rb + k1]) : (short)0;
      }
    }
#pragma unroll
    for (int nt = 0; nt < 4; ++nt) {
      int4 b0i = sB[L][nt * 2], b1i = sB[L][nt * 2 + 1];
      sh8 B0 = *(const sh8*)&b0i, B1 = *(const sh8*)&b1i;
      const int col = nt * 16 + c;
      f4 acc = { bi[nt], bi[nt], bi[nt], bi[nt] };
      acc = __builtin_amdgcn_mfma_f32_16x16x32_bf16(A0, B0, acc, 0, 0, 0);
      acc = __builtin_amdgcn_mfma_f32_16x16x32_bf16(A1, B1, acc, 0, 0, 0);
      if (col < TABW) {
        const float s = gsc(col);
#pragma unroll
        for (int r = 0; r < 4; ++r)
          st[w][q * 4 + r][col] = (_Float16)__ushort_as_half(
              __half_as_ushort(__float2half_rn(acc[r] * s)));
      }
    }
    __syncthreads();                         // wave-private region; barrier OK
    // coalesced store: 480 dwords = 16 rows x 30 dwords, contiguous in tab.
    {
      unsigned* dst = (unsigned*)(tab16 + (size_t)v0 * TABW);
      const char* srcb = (const char*)&st[w][0][0];
      for (int i = L; i < 480; i += 64) {
        const int row = i / 30, cp = i % 30;
        dst[i] = *(const unsigned*)(srcb + row * 136 + cp * 4);
      }
    }
    __syncthreads();
  }
}

// ONE batch element per wave; 100-step GRU in inline asm (r26, 118.5us,
// VERIFIED absmax 7.63e-06). Unchanged this round.
__global__ __launch_bounds__(256, 5) void gru_main(
    const int* __restrict__ x, const float* __restrict__ ws,
    const void* __restrict__ emb, void* __restrict__ out)
{
  const int isf = detect_isf(emb);   // output dtype only
  const int j = threadIdx.x & 63;
  const int e = __builtin_amdgcn_readfirstlane(blockIdx.x * 4 + (threadIdx.x >> 6));
  const int jc = j < TABW ? j : 0;

  const int* xr = x + (size_t)e * SEQ_T;
  const unsigned short* tab = (const unsigned short*)(ws + OFF_TAB);
  const int o1 = jc * 40;                    // 10 packed dwords per column
  const int jc2 = jc * 2;                    // byte offset of col jc in f16 tab row
  const int a1 = ((j - 20) & 63) * 4;        // bpermute addr: r -> h-lanes
  const int a2 = ((j + 40) & 63) * 4;        // bpermute addr: hc -> z-lanes
  const float br1 = ws[OFF_B1 + 60 + jc];    // prescaled
  const float bi2 = ws[OFF_B2 + jc];         // prescaled
  const float br2 = ws[OFF_B2 + 60 + jc];    // prescaled

  // per-wave LDS 256B: h1 pairs bytes 0-39, h2 pairs 40-79, trash 80-166.
  __shared__ char sbuf[1024];
  const unsigned lb = (unsigned)(uintptr_t)&sbuf[0] + (threadIdx.x >> 6) * 256;
  const int lmapT = 80 + 2 * (j - 20);
  const int wadA = (int)(lb + (j < 20 ? 2 * j : lmapT));
  const int wadB = (int)(lb + (j < 20 ? 40 + 2 * j : lmapT));
  const int rad = (int)lb;
  float h2out;

  asm volatile(
    // ---- packed f16 weights: U1P v10-19, W2P v20-29, U2P v30-39 ----
    "global_load_dwordx4 v[10:13], %[o1], %[wsp] offset:0\n\t"
    "global_load_dwordx4 v[14:17], %[o1], %[wsp] offset:16\n\t"
    "global_load_dwordx2 v[18:19], %[o1], %[wsp] offset:32\n\t"
    "v_add_u32 v44, 0x960, %[o1]\n\t"
    "v_add_u32 v45, 0x12c0, %[o1]\n\t"
    "global_load_dwordx4 v[20:23], v44, %[wsp] offset:0\n\t"
    "global_load_dwordx4 v[24:27], v44, %[wsp] offset:16\n\t"
    "global_load_dwordx2 v[28:29], v44, %[wsp] offset:32\n\t"
    "global_load_dwordx4 v[30:33], v45, %[wsp] offset:0\n\t"
    "global_load_dwordx4 v[34:37], v45, %[wsp] offset:16\n\t"
    "global_load_dwordx2 v[38:39], v45, %[wsp] offset:32\n\t"
    // ---- h masters zero ----
    "v_mov_b32 v40, 0\n\t"
    "v_mov_b32 v41, 0\n\t"
    // ---- prime: mx0->v52, mx1->v42, mx2->v43 (raw f16); idx3/4->s65/s68 --
    "s_load_dword s65, %[xp], 0x0\n\t"
    "s_load_dword s66, %[xp], 0x4\n\t"
    "s_load_dword s68, %[xp], 0x8\n\t"
    "s_waitcnt lgkmcnt(0)\n\t"
    "s_mul_i32 s65, s65, 120\n\t"
    "s_mul_i32 s66, s66, 120\n\t"
    "s_mul_i32 s68, s68, 120\n\t"
    "v_add_u32 v50, s65, %[jc2]\n\t"
    "global_load_ushort v52, v50, %[tabp]\n\t"
    "v_add_u32 v50, s66, %[jc2]\n\t"
    "global_load_ushort v42, v50, %[tabp]\n\t"
    "v_add_u32 v50, s68, %[jc2]\n\t"
    "global_load_ushort v43, v50, %[tabp]\n\t"
    "s_load_dword s65, %[xp], 0xc\n\t"     // idx3 (odd stream)
    "s_load_dword s68, %[xp], 0x10\n\t"    // idx4 (even stream)
    "s_movk_i32 s64, 0x14\n\t"             // next odd x-offset (idx5)
    "s_movk_i32 s69, 0x18\n\t"             // next even x-offset (idx6)
    "s_movk_i32 s67, 0x32\n\t"             // 50 unrolled iterations
    "s_waitcnt vmcnt(2)\n\t"               // weights + mx0 ready
    "v_cvt_f32_f16 v52, v52\n\t"           // mx0 -> f32 (prescaled)
    // ======== PROLOGUE: L1(0)  (h1(-1)=0 -> mh = br1'; mx0 = v52) ========
    "v_mov_b32 v44, %[br1]\n\t"
    "v_add_f32 v45, v52, v44\n\t"
    "v_exp_f32 v45, v45\n\t"
    "s_nop 1\n\t"
    "v_add_f32 v45, 1.0, v45\n\t"
    "v_rcp_f32 v45, v45\n\t"
    "s_nop 1\n\t"
    "ds_bpermute_b32 v46, %[a1], v45\n\t"
    "s_waitcnt lgkmcnt(0)\n\t"
    "v_fma_f32 v47, v46, v44, v52\n\t"
    "v_exp_f32 v47, v47\n\t"
    "s_nop 1\n\t"
    "v_add_f32 v47, 1.0, v47\n\t"
    "v_rcp_f32 v47, v47\n\t"
    "s_nop 1\n\t"
    "v_fma_f32 v47, -2.0, v47, 1.0\n\t"
    "ds_bpermute_b32 v46, %[a2], v47\n\t"
    "s_waitcnt lgkmcnt(0)\n\t"
    "v_sub_f32 v48, v40, v46\n\t"
    "v_fma_f32 v40, v45, v48, v46\n\t"     // h1(0)
    "v_cvt_f16_f32 v46, v40\n\t"
    "v_mov_b32 v54, 0\n\t"                 // h2(-1) = 0 region
    "ds_write_b16 %[wadA], v46\n\t"
    "ds_write_b16 %[wadB], v54\n\t"
    "ds_read_b128 v[56:59], %[rad]\n\t"
    "ds_read_b128 v[60:63], %[rad] offset:16\n\t"
    "ds_read_b128 v[64:67], %[rad] offset:32\n\t"
    "ds_read_b128 v[68:71], %[rad] offset:48\n\t"
    "ds_read_b128 v[72:75], %[rad] offset:64\n\t"
    // ======== LOOP k=0..49 ======== (7 DS tokens outstanding at top)
    "0:\n\t"
    // ---- HALF A: L2(2k) || L1(2k+1). h1 pairs v56-65, h2 pairs v66-75.
    "s_waitcnt lgkmcnt(2)\n\t"             // wA,wB,r1,r2,r3 done: h1 valid
    "v_dot2_f32_f16 v44, v56, v10, %[br1]\n\t"
    "v_dot2_f32_f16 v51, v56, v20, %[bi2]\n\t"
    "v_dot2_f32_f16 v44, v57, v11, v44\n\t"
    "v_dot2_f32_f16 v51, v57, v21, v51\n\t"
    "v_dot2_f32_f16 v44, v58, v12, v44\n\t"
    "v_dot2_f32_f16 v51, v58, v22, v51\n\t"
    "v_dot2_f32_f16 v44, v59, v13, v44\n\t"
    "v_dot2_f32_f16 v51, v59, v23, v51\n\t"
    "v_dot2_f32_f16 v44, v60, v14, v44\n\t"
    "v_dot2_f32_f16 v51, v60, v24, v51\n\t"
    "s_waitcnt lgkmcnt(0)\n\t"             // r4,r5 done: h2 valid
    "v_dot2_f32_f16 v52, v66, v30, %[br2]\n\t"
    "v_dot2_f32_f16 v44, v61, v15, v44\n\t"
    "v_dot2_f32_f16 v51, v61, v25, v51\n\t"
    "v_dot2_f32_f16 v52, v67, v31, v52\n\t"
    "v_dot2_f32_f16 v44, v62, v16, v44\n\t"
    "v_dot2_f32_f16 v51, v62, v26, v51\n\t"
    "v_dot2_f32_f16 v52, v68, v32, v52\n\t"
    "v_dot2_f32_f16 v44, v63, v17, v44\n\t"
    "v_dot2_f32_f16 v51, v63, v27, v51\n\t"
    "v_dot2_f32_f16 v52, v69, v33, v52\n\t"
    "v_dot2_f32_f16 v44, v64, v18, v44\n\t"
    "v_dot2_f32_f16 v51, v64, v28, v51\n\t"
    "v_dot2_f32_f16 v52, v70, v34, v52\n\t"
    "v_dot2_f32_f16 v44, v65, v19, v44\n\t"
    "v_dot2_f32_f16 v51, v65, v29, v51\n\t"
    "v_dot2_f32_f16 v52, v71, v35, v52\n\t"
    "v_dot2_f32_f16 v52, v72, v36, v52\n\t"
    "v_dot2_f32_f16 v52, v73, v37, v52\n\t"
    "v_dot2_f32_f16 v52, v74, v38, v52\n\t"
    "v_dot2_f32_f16 v52, v75, v39, v52\n\t"
    "s_waitcnt vmcnt(1)\n\t"               // mx(2k+1) raw f16 in v42
    "v_cvt_f32_f16 v42, v42\n\t"
    "v_add_f32 v45, v42, v44\n\t"
    "v_add_f32 v53, v51, v52\n\t"
    "v_exp_f32 v45, v45\n\t"
    "v_exp_f32 v53, v53\n\t"
    "v_add_f32 v45, 1.0, v45\n\t"
    "v_add_f32 v53, 1.0, v53\n\t"
    "v_rcp_f32 v45, v45\n\t"
    "v_rcp_f32 v53, v53\n\t"
    "ds_bpermute_b32 v46, %[a1], v45\n\t"
    "ds_bpermute_b32 v54, %[a1], v53\n\t"
    "s_mul_i32 s66, s65, 120\n\t"
    "v_add_u32 v50, s66, %[jc2]\n\t"
    "s_waitcnt lgkmcnt(0)\n\t"
    "v_fma_f32 v47, v46, v44, v42\n\t"     // hp1, last v42 use
    "v_fma_f32 v55, v54, v52, v51\n\t"     // hp2
    "global_load_ushort v42, v50, %[tabp]\n\t"  // mx(2k+3)
    "s_min_u32 s64, s64, 396\n\t"
    "s_load_dword s65, %[xp], s64\n\t"     // idx(2k+5)
    "s_add_u32 s64, s64, 8\n\t"
    "v_exp_f32 v47, v47\n\t"
    "v_exp_f32 v55, v55\n\t"
    "v_add_f32 v47, 1.0, v47\n\t"
    "v_add_f32 v55, 1.0, v55\n\t"
    "v_rcp_f32 v47, v47\n\t"
    "v_rcp_f32 v55, v55\n\t"
    "s_nop 0\n\t"
    "v_fma_f32 v47, -2.0, v47, 1.0\n\t"    // hc1
    "v_fma_f32 v55, -2.0, v55, 1.0\n\t"    // hc2
    "ds_bpermute_b32 v46, %[a2], v47\n\t"
    "ds_bpermute_b32 v54, %[a2], v55\n\t"
    "s_waitcnt lgkmcnt(0)\n\t"             // bperms + s_load retired
    "v_sub_f32 v48, v40, v46\n\t"
    "v_fma_f32 v40, v45, v48, v46\n\t"     // h1(2k+1)
    "v_sub_f32 v48, v41, v54\n\t"
    "v_fma_f32 v41, v53, v48, v54\n\t"     // h2(2k)
    "v_cvt_f16_f32 v46, v40\n\t"
    "v_cvt_f16_f32 v54, v41\n\t"
    "ds_write_b16 %[wadA], v46\n\t"
    "ds_write_b16 %[wadB], v54\n\t"
    "ds_read_b128 v[56:59], %[rad]\n\t"
    "ds_read_b128 v[60:63], %[rad] offset:16\n\t"
    "ds_read_b128 v[64:67], %[rad] offset:32\n\t"
    "ds_read_b128 v[68:71], %[rad] offset:48\n\t"
    "ds_read_b128 v[72:75], %[rad] offset:64\n\t"
    // ---- HALF B: L2(2k+1) || L1(2k+2). mx = v43. ----
    "s_waitcnt lgkmcnt(2)\n\t"
    "v_dot2_f32_f16 v44, v56, v10, %[br1]\n\t"
    "v_dot2_f32_f16 v51, v56, v20, %[bi2]\n\t"
    "v_dot2_f32_f16 v44, v57, v11, v44\n\t"
    "v_dot2_f32_f16 v51, v57, v21, v51\n\t"
    "v_dot2_f32_f16 v44, v58, v12, v44\n\t"
    "v_dot2_f32_f16 v51, v58, v22, v51\n\t"
    "v_dot2_f32_f16 v44, v59, v13, v44\n\t"
    "v_dot2_f32_f16 v51, v59, v23, v51\n\t"
    "v_dot2_f32_f16 v44, v60, v14, v44\n\t"
    "v_dot2_f32_f16 v51, v60, v24, v51\n\t"
    "s_waitcnt lgkmcnt(0)\n\t"
    "v_dot2_f32_f16 v52, v66, v30, %[br2]\n\t"
    "v_dot2_f32_f16 v44, v61, v15, v44\n\t"
    "v_dot2_f32_f16 v51, v61, v25, v51\n\t"
    "v_dot2_f32_f16 v52, v67, v31, v52\n\t"
    "v_dot2_f32_f16 v44, v62, v16, v44\n\t"
    "v_dot2_f32_f16 v51, v62, v26, v51\n\t"
    "v_dot2_f32_f16 v52, v68, v32, v52\n\t"
    "v_dot2_f32_f16 v44, v63, v17, v44\n\t"
    "v_dot2_f32_f16 v51, v63, v27, v51\n\t"
    "v_dot2_f32_f16 v52, v69, v33, v52\n\t"
    "v_dot2_f32_f16 v44, v64, v18, v44\n\t"
    "v_dot2_f32_f16 v51, v64, v28, v51\n\t"
    "v_dot2_f32_f16 v52, v70, v34, v52\n\t"
    "v_dot2_f32_f16 v44, v65, v19, v44\n\t"
    "v_dot2_f32_f16 v51, v65, v29, v51\n\t"
    "v_dot2_f32_f16 v52, v71, v35, v52\n\t"
    "v_dot2_f32_f16 v52, v72, v36, v52\n\t"
    "v_dot2_f32_f16 v52, v73, v37, v52\n\t"
    "v_dot2_f32_f16 v52, v74, v38, v52\n\t"
    "v_dot2_f32_f16 v52, v75, v39, v52\n\t"
    "s_waitcnt vmcnt(1)\n\t"               // mx(2k+2) raw f16 in v43
    "v_cvt_f32_f16 v43, v43\n\t"
    "v_add_f32 v45, v43, v44\n\t"
    "v_add_f32 v53, v51, v52\n\t"
    "v_exp_f32 v45, v45\n\t"
    "v_exp_f32 v53, v53\n\t"
    "v_add_f32 v45, 1.0, v45\n\t"
    "v_add_f32 v53, 1.0, v53\n\t"
    "v_rcp_f32 v45, v45\n\t"
    "v_rcp_f32 v53, v53\n\t"
    "ds_bpermute_b32 v46, %[a1], v45\n\t"
    "ds_bpermute_b32 v54, %[a1], v53\n\t"
    "s_mul_i32 s66, s68, 120\n\t"
    "v_add_u32 v50, s66, %[jc2]\n\t"
    "s_waitcnt lgkmcnt(0)\n\t"
    "v_fma_f32 v47, v46, v44, v43\n\t"     // hp1, last v43 use
    "v_fma_f32 v55, v54, v52, v51\n\t"     // hp2
    "global_load_ushort v43, v50, %[tabp]\n\t"  // mx(2k+4)
    "s_min_u32 s69, s69, 392\n\t"
    "s_load_dword s68, %[xp], s69\n\t"     // idx(2k+6)
    "s_add_u32 s69, s69, 8\n\t"
    "v_exp_f32 v47, v47\n\t"
    "v_exp_f32 v55, v55\n\t"
    "v_add_f32 v47, 1.0, v47\n\t"
    "v_add_f32 v55, 1.0, v55\n\t"
    "v_rcp_f32 v47, v47\n\t"
    "v_rcp_f32 v55, v55\n\t"
    "s_nop 0\n\t"
    "v_fma_f32 v47, -2.0, v47, 1.0\n\t"
    "v_fma_f32 v55, -2.0, v55, 1.0\n\t"
    "ds_bpermute_b32 v46, %[a2], v47\n\t"
    "ds_bpermute_b32 v54, %[a2], v55\n\t"
    "s_waitcnt lgkmcnt(0)\n\t"
    "v_sub_f32 v48, v40, v46\n\t"
    "v_fma_f32 v40, v45, v48, v46\n\t"     // h1(2k+2)
    "v_sub_f32 v48, v41, v54\n\t"
    "v_fma_f32 v41, v53, v48, v54\n\t"     // h2(2k+1)
    "v_cvt_f16_f32 v46, v40\n\t"
    "v_cvt_f16_f32 v54, v41\n\t"
    "ds_write_b16 %[wadA], v46\n\t"
    "ds_write_b16 %[wadB], v54\n\t"
    "ds_read_b128 v[56:59], %[rad]\n\t"
    "ds_read_b128 v[60:63], %[rad] offset:16\n\t"
    "ds_read_b128 v[64:67], %[rad] offset:32\n\t"
    "ds_read_b128 v[68:71], %[rad] offset:48\n\t"
    "ds_read_b128 v[72:75], %[rad] offset:64\n\t"
    "s_sub_u32 s67, s67, 1\n\t"
    "s_cmp_lg_u32 s67, 0\n\t"
    "s_cbranch_scc1 0b\n\t"
    "s_waitcnt vmcnt(0) lgkmcnt(0)\n\t"
    "v_mov_b32 %[h2o], v41\n\t"
    : [h2o] "=v"(h2out)
    : [wsp] "s"(ws), [xp] "s"(xr), [tabp] "s"(tab),
      [o1] "v"(o1), [jc2] "v"(jc2), [a1] "v"(a1), [a2] "v"(a2),
      [br1] "v"(br1), [bi2] "v"(bi2), [br2] "v"(br2),
      [wadA] "v"(wadA), [wadB] "v"(wadB), [rad] "v"(rad)
    : "memory", "vcc", "scc",
      "v10","v11","v12","v13","v14","v15","v16","v17","v18","v19",
      "v20","v21","v22","v23","v24","v25","v26","v27","v28","v29",
      "v30","v31","v32","v33","v34","v35","v36","v37","v38","v39",
      "v40","v41","v42","v43","v44","v45","v46","v47","v48","v50",
      "v51","v52","v53","v54","v55",
      "v56","v57","v58","v59","v60","v61","v62","v63","v64","v65",
      "v66","v67","v68","v69","v70","v71","v72","v73","v74","v75",
      "s64","s65","s66","s67","s68","s69");

  // ---- dense: logits = h2 @ Wd + bd (h2 master fp32 in lanes 0..19) ----
  if (j < 15) {
    float a = ws[OFF_BD + j];
#pragma unroll
    for (int k = 0; k < HID; ++k)
      a = fmaf(rdl(h2out, k), ws[OFF_WD + k * 15 + j], a);
    if (isf) ((float*)out)[(size_t)e * 15 + j] = a;
    else ((__hip_bfloat16*)out)[(size_t)e * 15 + j] = __float2bfloat16(a);
  }
}

extern "C" void kernel_launch(void* const* d_in, const int* in_sizes, int n_in,
                              void* d_out, int out_size, void* d_ws, size_t ws_size,
                              hipStream_t stream) {
  const int* x    = (const int*)d_in[0];
  const void* emb = d_in[1];
  const void* W1  = d_in[2];
  const void* U1  = d_in[3];
  const void* b1  = d_in[4];
  const void* W2  = d_in[5];
  const void* U2  = d_in[6];
  const void* b2  = d_in[7];
  const void* Wd  = d_in[8];
  const void* bd  = d_in[9];
  float* ws = (float*)d_ws;   // 6.02 MB used (12 MB proven safe)

  build_table<<<BBLK, 256, 0, stream>>>(
      emb, W1, b1, U1, W2, U2, b2, Wd, bd, ws);
  gru_main<<<2048, 256, 0, stream>>>(x, ws, emb, d_out);
}